// Round 1
// 520.219 us; speedup vs baseline: 1.0270x; 1.0270x over previous
//
#include <hip/hip_runtime.h>

// Problem constants
#define NN 50000
#define EE 1600000
#define FF 128
#define HH 64
#define CC 40

// deg hist: 64 edge-chunks x 4 node-slices = 256 blocks
#define NCH 64
#define CHE (EE / NCH)         // 25000
#define NSL 4
#define SLN (NN / NSL)         // 12500

// bucket sort: 250 producers x 250 dst-slices (200 nodes each), capacity 64
#define PA 250
#define EPP (EE / PA)          // 6400
#define SB 250
#define SLNB 200               // NN / SB
#define BCAP 64

// ---------- bf16 helpers (storage-only; math in fp32) ----------
static __device__ __forceinline__ float bf2f(unsigned short u) {
    union { unsigned int i; float f; } c; c.i = ((unsigned int)u) << 16; return c.f;
}
static __device__ __forceinline__ unsigned short f2bf(float x) {  // RNE
    union { float f; unsigned int i; } c; c.f = x;
    unsigned int r = c.i + 0x7FFFu + ((c.i >> 16) & 1u);
    return (unsigned short)(r >> 16);
}

// MFMA fragment types (guide: ext_vector(8) short == 8 bf16, 4 VGPRs)
typedef __attribute__((ext_vector_type(8))) short bf16x8;
typedef __attribute__((ext_vector_type(4))) float f32x4;
union BF8 { bf16x8 v; unsigned short u[8]; };

// ---------- deg histogram ----------
__global__ __launch_bounds__(1024) void deg_hist_kernel(
    const int* __restrict__ src, const float* __restrict__ w,
    float* __restrict__ pdeg) {
    __shared__ float ldeg[SLN];
    int s = blockIdx.x % NSL;
    int c = blockIdx.x / NSL;
    int base = s * SLN;
    for (int i = threadIdx.x; i < SLN; i += 1024) ldeg[i] = 0.f;
    __syncthreads();
    int e0 = c * CHE;
    for (int e = e0 + threadIdx.x; e < e0 + CHE; e += 1024) {
        int se = src[e];
        unsigned us = (unsigned)(se - base);
        if (us < SLN) atomicAdd(&ldeg[us], w[e]);
    }
    __syncthreads();
    for (int i = threadIdx.x; i < SLN; i += 1024)
        pdeg[(size_t)c * NN + base + i] = ldeg[i];
}

__global__ void reduce_kernel(const float* __restrict__ pdeg,
                              float* __restrict__ dis, float* __restrict__ diag) {
    int n = blockIdx.x * blockDim.x + threadIdx.x;
    if (n >= NN) return;
    float dsum = 0.f;
    for (int c = 0; c < NCH; ++c) dsum += pdeg[(size_t)c * NN + n];
    dis[n]  = (dsum > 0.f) ? rsqrtf(fmaxf(dsum, 1e-12f)) : 0.f;
    diag[n] = (dsum > 0.f) ? 0.f : -1.f;
}

// ---------- phase A: bin edges by dst-slice ----------
__global__ __launch_bounds__(256) void bucketA_kernel(
    const int* __restrict__ src, const int* __restrict__ dst,
    const float* __restrict__ w, const float* __restrict__ dis,
    uint2* __restrict__ buckets, int* __restrict__ counts) {
    __shared__ int lcnt[SB];
    int p = blockIdx.x;
    for (int i = threadIdx.x; i < SB; i += 256) lcnt[i] = 0;
    __syncthreads();
    int e0 = p * EPP;
    for (int e = e0 + threadIdx.x; e < e0 + EPP; e += 256) {
        int de = dst[e], se = src[e];
        int sl = de / SLNB;
        int dl = de - sl * SLNB;
        float wn = -dis[se] * w[e] * dis[de];
        unsigned lo = (unsigned)se | ((unsigned)f2bf(wn) << 16);
        int idx = atomicAdd(&lcnt[sl], 1);
        buckets[((size_t)p * SB + sl) * BCAP + idx] = make_uint2(lo, (unsigned)dl);
    }
    __syncthreads();
    for (int i = threadIdx.x; i < SB; i += 256) counts[p * SB + i] = lcnt[i];
}

// ---------- exclusive scan of per-slice totals ----------
__global__ void scanS_kernel(const int* __restrict__ counts, int* __restrict__ sbase) {
    __shared__ int sh[256];
    int t = threadIdx.x;
    int total = 0;
    if (t < SB)
        for (int p = 0; p < PA; ++p) total += counts[p * SB + t];
    sh[t] = total;
    __syncthreads();
    for (int off = 1; off < 256; off <<= 1) {
        int x = (t >= off) ? sh[t - off] : 0;
        __syncthreads();
        sh[t] += x;
        __syncthreads();
    }
    if (t < SB) sbase[t] = sh[t] - total;
    if (t == SB - 1) sbase[SB] = sh[t];
}

// ---------- phase B v2: counts in LDS + 16-lane bucket subgroups ----------
__global__ __launch_bounds__(256) void bucketB_kernel(
    const uint2* __restrict__ buckets, const int* __restrict__ counts,
    const int* __restrict__ sbase,
    int* __restrict__ row_start, unsigned int* __restrict__ csr) {
    __shared__ int lcounts[PA];
    __shared__ int lhist[SLNB];
    __shared__ int sh[256];
    int s = blockIdx.x;
    int t = threadIdx.x;
    if (t < PA) lcounts[t] = counts[t * SB + s];
    for (int i = t; i < SLNB; i += 256) lhist[i] = 0;
    __syncthreads();
    int g = t >> 4, l16 = t & 15;   // 16 subgroups x 16 lanes
    for (int p = g; p < PA; p += 16) {
        int c = lcounts[p];
        const uint2* b = buckets + ((size_t)p * SB + s) * BCAP;
        for (int i = l16; i < c; i += 16)
            atomicAdd(&lhist[b[i].y], 1);
    }
    __syncthreads();
    int v = (t < SLNB) ? lhist[t] : 0;
    sh[t] = v;
    __syncthreads();
    for (int off = 1; off < 256; off <<= 1) {
        int x = (t >= off) ? sh[t - off] : 0;
        __syncthreads();
        sh[t] += x;
        __syncthreads();
    }
    int base = sbase[s];
    if (t < SLNB) {
        int excl = sh[t] - v;
        row_start[s * SLNB + t] = base + excl;
        lhist[t] = base + excl;          // absolute cursor
    }
    if (s == SB - 1 && t == 0) row_start[NN] = sbase[SB];
    __syncthreads();
    for (int p = g; p < PA; p += 16) {
        int c = lcounts[p];
        const uint2* b = buckets + ((size_t)p * SB + s) * BCAP;
        for (int i = l16; i < c; i += 16) {
            uint2 en = b[i];
            int pos = atomicAdd(&lhist[en.y], 1);
            csr[pos] = en.x;
        }
    }
}

// ---------- propagation: all operands bf16 slabs [N,64] ----------
template <int FACT, typename OUT_T>
__global__ __launch_bounds__(256) void prop2_kernel(
    const unsigned short* __restrict__ a, float alphaL,
    const unsigned short* __restrict__ p1, float beta1,
    const unsigned short* __restrict__ p2, float beta2,
    const float* __restrict__ bias, int doRelu, int FOUT, int outStride,
    const float* __restrict__ diag, const int* __restrict__ rs,
    const unsigned int* __restrict__ csr, OUT_T* __restrict__ out) {
    int lane = threadIdx.x & 63;
    int wave = threadIdx.x >> 6;
    int n = blockIdx.x * 4 + wave;   // NN divisible by 4
    int f = lane;
    float acc = 0.f;
    if (f < FACT) {
        acc = diag[n] * bf2f(a[(size_t)n * 64 + f]);
        int j0 = rs[n], j1 = rs[n + 1];
        int j = j0;
        for (; j + 8 <= j1; j += 8) {
            unsigned cw[8];
            #pragma unroll
            for (int u = 0; u < 8; ++u) cw[u] = csr[j + u];
            float v[8];
            #pragma unroll
            for (int u = 0; u < 8; ++u)
                v[u] = bf2f(a[(size_t)(cw[u] & 0xFFFFu) * 64 + f]);
            #pragma unroll
            for (int u = 0; u < 8; ++u)
                acc = fmaf(bf2f((unsigned short)(cw[u] >> 16)), v[u], acc);
        }
        for (; j < j1; ++j) {
            unsigned cw = csr[j];
            acc = fmaf(bf2f((unsigned short)(cw >> 16)),
                       bf2f(a[(size_t)(cw & 0xFFFFu) * 64 + f]), acc);
        }
    }
    if (f < FOUT) {
        float r = alphaL * acc + beta1 * bf2f(p1[(size_t)n * 64 + f]);
        if (beta2 != 0.f) r = fmaf(beta2, bf2f(p2[(size_t)n * 64 + f]), r);
        if (bias) r += bias[f];
        if (doRelu) r = fmaxf(r, 0.f);
        OUT_T o;
        if constexpr (sizeof(OUT_T) == 2) o = f2bf(r); else o = r;
        out[(size_t)n * outStride + f] = o;
    }
}

// ---------- weight prep: transposed bf16 hi/lo tables, K-contiguous ----------
// W1t[(ct*64+j)*128 + kk] = W1[(ct*128+kk)*64 + j]    (32768 elems)
// W2t[(kt*64+j)*64  + kk] = (j<40) ? W2[(kt*64+kk)*40 + j] : 0   (16384 elems)
__global__ __launch_bounds__(256) void convw_kernel(
    const float* __restrict__ W1, const float* __restrict__ W2,
    unsigned short* __restrict__ W1t_hi, unsigned short* __restrict__ W1t_lo,
    unsigned short* __restrict__ W2t_hi, unsigned short* __restrict__ W2t_lo) {
    int tid = blockIdx.x * 256 + threadIdx.x;
    if (tid < 512 * 64) {
        int row = tid >> 7, kk = tid & 127;      // row = ct*64 + j
        int ct = row >> 6, j = row & 63;
        float v = W1[((size_t)(ct * 128 + kk)) * 64 + j];
        unsigned short h = f2bf(v);
        W1t_hi[tid] = h;
        W1t_lo[tid] = f2bf(v - bf2f(h));
    } else {
        int t2 = tid - 512 * 64;
        if (t2 >= 4 * 64 * 64) return;
        int row = t2 >> 6, kk = t2 & 63;         // row = kt*64 + j
        int kt = row >> 6, j = row & 63;
        float v = (j < CC) ? W2[((size_t)(kt * 64 + kk)) * CC + j] : 0.f;
        unsigned short h = f2bf(v);
        W2t_hi[t2] = h;
        W2t_lo[t2] = f2bf(v - bf2f(h));
    }
}

// ---------- MFMA GEMM: A[NN][KF*32] fp32 (split hi/lo in-reg) @ Wt -> bf16 slabs ----------
// KF = number of 32-wide K fragments. Wave w computes slab w (64 output cols).
// Split-precision: A*B ~= Ah*Bh + Ah*Bl + Al*Bh  (fp32-equivalent accuracy).
template <int KF>
__global__ __launch_bounds__(256) void gemm_mfma_kernel(
    const float* __restrict__ A, const unsigned short* __restrict__ Wt_hi,
    const unsigned short* __restrict__ Wt_lo, unsigned short* __restrict__ Yb) {
    constexpr int KK = KF * 32;                 // A row length == Wt row length
    int lane = threadIdx.x & 63;
    int ct   = threadIdx.x >> 6;                // wave = output slab
    int l15  = lane & 15;
    int lg   = lane >> 4;
    int m0   = blockIdx.x * 32;

    f32x4 acc[2][4];
    #pragma unroll
    for (int i = 0; i < 2; ++i)
        #pragma unroll
        for (int j = 0; j < 4; ++j)
            acc[i][j] = (f32x4){0.f, 0.f, 0.f, 0.f};

    #pragma unroll
    for (int kf = 0; kf < KF; ++kf) {
        int k0 = kf * 32 + lg * 8;
        // B fragments: column j = ct*64 + nf*16 + l15, 8 K-contiguous bf16 (16B load)
        BF8 bh[4], bl[4];
        #pragma unroll
        for (int nf = 0; nf < 4; ++nf) {
            size_t addr = (size_t)(ct * 64 + nf * 16 + l15) * KK + k0;
            bh[nf].v = *reinterpret_cast<const bf16x8*>(Wt_hi + addr);
            bl[nf].v = *reinterpret_cast<const bf16x8*>(Wt_lo + addr);
        }
        // A fragments: row m0 + ms*16 + l15, 8 K-contiguous fp32 -> hi/lo bf16
        BF8 ah[2], al[2];
        #pragma unroll
        for (int ms = 0; ms < 2; ++ms) {
            int n = m0 + ms * 16 + l15;
            if (n >= NN) n = NN - 1;             // clamp (stores are guarded)
            const float* ap = A + (size_t)n * KK + k0;
            float4 f0 = *(const float4*)(ap);
            float4 f1 = *(const float4*)(ap + 4);
            float fv[8] = {f0.x, f0.y, f0.z, f0.w, f1.x, f1.y, f1.z, f1.w};
            #pragma unroll
            for (int u = 0; u < 8; ++u) {
                unsigned short h = f2bf(fv[u]);
                ah[ms].u[u] = h;
                al[ms].u[u] = f2bf(fv[u] - bf2f(h));
            }
        }
        #pragma unroll
        for (int ms = 0; ms < 2; ++ms)
            #pragma unroll
            for (int nf = 0; nf < 4; ++nf) {
                acc[ms][nf] = __builtin_amdgcn_mfma_f32_16x16x32_bf16(
                    ah[ms].v, bh[nf].v, acc[ms][nf], 0, 0, 0);
                acc[ms][nf] = __builtin_amdgcn_mfma_f32_16x16x32_bf16(
                    ah[ms].v, bl[nf].v, acc[ms][nf], 0, 0, 0);
                acc[ms][nf] = __builtin_amdgcn_mfma_f32_16x16x32_bf16(
                    al[ms].v, bh[nf].v, acc[ms][nf], 0, 0, 0);
            }
    }

    // store: D col = l15, row = lg*4 + r  (m89-verified C/D layout)
    unsigned short* slab = Yb + (size_t)ct * NN * 64;
    #pragma unroll
    for (int ms = 0; ms < 2; ++ms)
        #pragma unroll
        for (int r = 0; r < 4; ++r) {
            int n = m0 + ms * 16 + lg * 4 + r;
            if (n < NN) {
                #pragma unroll
                for (int nf = 0; nf < 4; ++nf)
                    slab[(size_t)n * 64 + nf * 16 + l15] = f2bf(acc[ms][nf][r]);
            }
        }
}

// ---------- launcher ----------
extern "C" void kernel_launch(void* const* d_in, const int* in_sizes, int n_in,
                              void* d_out, int out_size, void* d_ws, size_t ws_size,
                              hipStream_t stream) {
    const float* x    = (const float*)d_in[0];
    const int*   eidx = (const int*)d_in[1];
    const float* ew   = (const float*)d_in[2];
    const float* W1   = (const float*)d_in[3];
    const float* b1   = (const float*)d_in[4];
    const float* W2   = (const float*)d_in[5];
    const float* b2   = (const float*)d_in[6];
    float* out = (float*)d_out;

    const int* src = eidx;
    const int* dst = eidx + EE;

    // workspace carve-up  (total ~91 MB)
    float* p = (float*)d_ws;
    unsigned int* csr = (unsigned int*)p;  p += (size_t)EE;           // 6.4 MB
    float* dis  = p;                  p += ((NN + 63) / 64) * 64;
    float* diag = p;                  p += ((NN + 63) / 64) * 64;
    unsigned short* Yb = (unsigned short*)p;  p += (size_t)NN * 128;  // 4 bf16 slabs, 25.6 MB
    unsigned short* u  = (unsigned short*)p;  p += (size_t)NN * 32;   // bf16 [N,64], 6.4 MB
    unsigned short* v  = (unsigned short*)p;  p += (size_t)NN * 32;   // 6.4 MB
    float* h    = p;                  p += (size_t)NN * 64;           // fp32 [N,64], 12.8 MB
    float* scratch = p;               p += (size_t)PA * SB * BCAP * 2; // 32 MB (buckets)
    int* row_start = (int*)p;             // NN+1
    int* counts    = row_start + NN + 1;  // PA*SB
    int* sbase     = counts + PA * SB;    // SB+1

    // setup scratch: pdeg (12.8 MB) and buckets (32 MB) SHARE the 32 MB region.
    // Legal: pdeg dead after reduce; buckets dead after bucketB; W-tables (192 KB)
    // are written by convw AFTER bucketB and only read by the gemm kernels.
    float* pdeg    = scratch;             // 64*NN floats = 12.8 MB
    uint2* buckets = (uint2*)scratch;     // PA*SB*BCAP*8 B = 32 MB
    unsigned short* W1t_hi = (unsigned short*)scratch;   // 32768 bf16
    unsigned short* W1t_lo = W1t_hi + 512 * 64;
    unsigned short* W2t_hi = W1t_lo + 512 * 64;          // 16384 bf16
    unsigned short* W2t_lo = W2t_hi + 4 * 64 * 64;
    // layer-1 slab views
    unsigned short* y0b = Yb;
    unsigned short* y1b = Yb + (size_t)1 * NN * 64;
    unsigned short* y2b = Yb + (size_t)2 * NN * 64;
    unsigned short* y3b = Yb + (size_t)3 * NN * 64;
    // layer-2 slabs alias Yb (y-slabs dead after h)
    unsigned short* Zb = Yb;
    unsigned short* z0 = Zb;
    unsigned short* z1 = Zb + (size_t)1 * NN * 64;
    unsigned short* z2 = Zb + (size_t)2 * NN * 64;
    unsigned short* z3 = Zb + (size_t)3 * NN * 64;
    unsigned short* u2 = u;
    unsigned short* v2 = v;

    const int B = 256;
    deg_hist_kernel<<<NCH * NSL, 1024, 0, stream>>>(src, ew, pdeg);
    reduce_kernel<<<(NN + B - 1) / B, B, 0, stream>>>(pdeg, dis, diag);
    bucketA_kernel<<<PA, 256, 0, stream>>>(src, dst, ew, dis, buckets, counts);
    scanS_kernel<<<1, 256, 0, stream>>>(counts, sbase);
    bucketB_kernel<<<SB, 256, 0, stream>>>(buckets, counts, sbase, row_start, csr);
    convw_kernel<<<192, 256, 0, stream>>>(W1, W2, W1t_hi, W1t_lo, W2t_hi, W2t_lo);

    int pgrid = NN / 4;
    int ggrid = (NN + 31) / 32;

    // ---- layer 1: MFMA-project to bf16 slabs, then 3 full-width props ----
    gemm_mfma_kernel<4><<<ggrid, 256, 0, stream>>>(x, W1t_hi, W1t_lo, Yb);
    prop2_kernel<64, unsigned short><<<pgrid, 256, 0, stream>>>(
        y3b, 4.f, y2b, 2.f, nullptr, 0.f,
        nullptr, 0, 64, 64, diag, row_start, csr, u);          // u = 4*L(y3) + 2*y2
    prop2_kernel<64, unsigned short><<<pgrid, 256, 0, stream>>>(
        u, 1.f, y1b, 1.f, y3b, -3.f,
        nullptr, 0, 64, 64, diag, row_start, csr, v);          // v = L(u) + y1 - 3*y3
    prop2_kernel<64, float><<<pgrid, 256, 0, stream>>>(
        v, 1.f, y0b, 1.f, y2b, -1.f,
        b1, 1, 64, 64, diag, row_start, csr, h);               // h = relu(L(v)+y0-y2+b1)

    // ---- layer 2: MFMA-project (cols 40..63 auto-zero via padded Wt), 3 props ----
    gemm_mfma_kernel<2><<<ggrid, 256, 0, stream>>>(h, W2t_hi, W2t_lo, Zb);
    prop2_kernel<48, unsigned short><<<pgrid, 256, 0, stream>>>(
        z3, 4.f, z2, 2.f, nullptr, 0.f,
        nullptr, 0, 48, 64, diag, row_start, csr, u2);         // u2 = 4*L(z3) + 2*z2
    prop2_kernel<48, unsigned short><<<pgrid, 256, 0, stream>>>(
        u2, 1.f, z1, 1.f, z3, -3.f,
        nullptr, 0, 48, 64, diag, row_start, csr, v2);         // v2 = L(u2) + z1 - 3*z3
    prop2_kernel<48, float><<<pgrid, 256, 0, stream>>>(
        v2, 1.f, z0, 1.f, z2, -1.f,
        b2, 0, 40, 40, diag, row_start, csr, out);             // out = L(v2)+z0-z2+b2
}

// Round 2
// 513.315 us; speedup vs baseline: 1.0408x; 1.0135x over previous
//
#include <hip/hip_runtime.h>

// Problem constants
#define NN 50000
#define EE 1600000
#define FF 128
#define HH 64
#define CC 40

// deg hist: 64 edge-chunks x 4 node-slices = 256 blocks
#define NCH 64
#define CHE (EE / NCH)         // 25000
#define NSL 4
#define SLN (NN / NSL)         // 12500

// bucket sort: 250 producers x 250 dst-slices (200 nodes each), capacity 64
#define PA 250
#define EPP (EE / PA)          // 6400
#define SB 250
#define SLNB 200               // NN / SB
#define BCAP 64

// half-slab: every feature slab is [2][NN][32] (3.2 MB halves -> per-XCD L2 resident)
#define HALFE ((size_t)NN * 32)

// ---------- bf16 helpers (storage-only; math in fp32) ----------
static __device__ __forceinline__ float bf2f(unsigned short u) {
    union { unsigned int i; float f; } c; c.i = ((unsigned int)u) << 16; return c.f;
}
static __device__ __forceinline__ unsigned short f2bf(float x) {  // RNE
    union { float f; unsigned int i; } c; c.f = x;
    unsigned int r = c.i + 0x7FFFu + ((c.i >> 16) & 1u);
    return (unsigned short)(r >> 16);
}

// MFMA fragment types
typedef __attribute__((ext_vector_type(8))) short bf16x8;
typedef __attribute__((ext_vector_type(4))) float f32x4;
union BF8 { bf16x8 v; unsigned short u[8]; };

// ---------- deg histogram ----------
__global__ __launch_bounds__(1024) void deg_hist_kernel(
    const int* __restrict__ src, const float* __restrict__ w,
    float* __restrict__ pdeg) {
    __shared__ float ldeg[SLN];
    int s = blockIdx.x % NSL;
    int c = blockIdx.x / NSL;
    int base = s * SLN;
    for (int i = threadIdx.x; i < SLN; i += 1024) ldeg[i] = 0.f;
    __syncthreads();
    int e0 = c * CHE;
    for (int e = e0 + threadIdx.x; e < e0 + CHE; e += 1024) {
        int se = src[e];
        unsigned us = (unsigned)(se - base);
        if (us < SLN) atomicAdd(&ldeg[us], w[e]);
    }
    __syncthreads();
    for (int i = threadIdx.x; i < SLN; i += 1024)
        pdeg[(size_t)c * NN + base + i] = ldeg[i];
}

__global__ void reduce_kernel(const float* __restrict__ pdeg,
                              float* __restrict__ dis, float* __restrict__ diag) {
    int n = blockIdx.x * blockDim.x + threadIdx.x;
    if (n >= NN) return;
    float dsum = 0.f;
    for (int c = 0; c < NCH; ++c) dsum += pdeg[(size_t)c * NN + n];
    dis[n]  = (dsum > 0.f) ? rsqrtf(fmaxf(dsum, 1e-12f)) : 0.f;
    diag[n] = (dsum > 0.f) ? 0.f : -1.f;
}

// ---------- phase A: bin edges by dst-slice ----------
__global__ __launch_bounds__(256) void bucketA_kernel(
    const int* __restrict__ src, const int* __restrict__ dst,
    const float* __restrict__ w, const float* __restrict__ dis,
    uint2* __restrict__ buckets, int* __restrict__ counts) {
    __shared__ int lcnt[SB];
    int p = blockIdx.x;
    for (int i = threadIdx.x; i < SB; i += 256) lcnt[i] = 0;
    __syncthreads();
    int e0 = p * EPP;
    for (int e = e0 + threadIdx.x; e < e0 + EPP; e += 256) {
        int de = dst[e], se = src[e];
        int sl = de / SLNB;
        int dl = de - sl * SLNB;
        float wn = -dis[se] * w[e] * dis[de];
        unsigned lo = (unsigned)se | ((unsigned)f2bf(wn) << 16);
        int idx = atomicAdd(&lcnt[sl], 1);
        buckets[((size_t)p * SB + sl) * BCAP + idx] = make_uint2(lo, (unsigned)dl);
    }
    __syncthreads();
    for (int i = threadIdx.x; i < SB; i += 256) counts[p * SB + i] = lcnt[i];
}

// ---------- exclusive scan of per-slice totals ----------
__global__ void scanS_kernel(const int* __restrict__ counts, int* __restrict__ sbase) {
    __shared__ int sh[256];
    int t = threadIdx.x;
    int total = 0;
    if (t < SB)
        for (int p = 0; p < PA; ++p) total += counts[p * SB + t];
    sh[t] = total;
    __syncthreads();
    for (int off = 1; off < 256; off <<= 1) {
        int x = (t >= off) ? sh[t - off] : 0;
        __syncthreads();
        sh[t] += x;
        __syncthreads();
    }
    if (t < SB) sbase[t] = sh[t] - total;
    if (t == SB - 1) sbase[SB] = sh[t];
}

// ---------- phase B v2: counts in LDS + 16-lane bucket subgroups ----------
__global__ __launch_bounds__(256) void bucketB_kernel(
    const uint2* __restrict__ buckets, const int* __restrict__ counts,
    const int* __restrict__ sbase,
    int* __restrict__ row_start, unsigned int* __restrict__ csr) {
    __shared__ int lcounts[PA];
    __shared__ int lhist[SLNB];
    __shared__ int sh[256];
    int s = blockIdx.x;
    int t = threadIdx.x;
    if (t < PA) lcounts[t] = counts[t * SB + s];
    for (int i = t; i < SLNB; i += 256) lhist[i] = 0;
    __syncthreads();
    int g = t >> 4, l16 = t & 15;   // 16 subgroups x 16 lanes
    for (int p = g; p < PA; p += 16) {
        int c = lcounts[p];
        const uint2* b = buckets + ((size_t)p * SB + s) * BCAP;
        for (int i = l16; i < c; i += 16)
            atomicAdd(&lhist[b[i].y], 1);
    }
    __syncthreads();
    int v = (t < SLNB) ? lhist[t] : 0;
    sh[t] = v;
    __syncthreads();
    for (int off = 1; off < 256; off <<= 1) {
        int x = (t >= off) ? sh[t - off] : 0;
        __syncthreads();
        sh[t] += x;
        __syncthreads();
    }
    int base = sbase[s];
    if (t < SLNB) {
        int excl = sh[t] - v;
        row_start[s * SLNB + t] = base + excl;
        lhist[t] = base + excl;          // absolute cursor
    }
    if (s == SB - 1 && t == 0) row_start[NN] = sbase[SB];
    __syncthreads();
    for (int p = g; p < PA; p += 16) {
        int c = lcounts[p];
        const uint2* b = buckets + ((size_t)p * SB + s) * BCAP;
        for (int i = l16; i < c; i += 16) {
            uint2 en = b[i];
            int pos = atomicAdd(&lhist[en.y], 1);
            csr[pos] = en.x;
        }
    }
}

// ---------- propagation on half-slabs [2][N][32] ----------
// Pass p is picked from blockIdx%8 so (with round-robin block->XCD mapping) each
// XCD gathers from only ONE 3.2 MB half => L2-resident gather working set.
// FACT=64: halves 32/32 on XCD split 4/4.  FACT=48: halves 32/16 on split 5/3.
template <int FACT, typename OUT_T, int FINAL>
__global__ __launch_bounds__(256) void prop3_kernel(
    const unsigned short* __restrict__ a, float alphaL,
    const unsigned short* __restrict__ p1, float beta1,
    const unsigned short* __restrict__ p2, float beta2,
    const float* __restrict__ bias, int doRelu,
    const float* __restrict__ diag, const int* __restrict__ rs,
    const unsigned int* __restrict__ csr, OUT_T* __restrict__ out) {

    int bid = blockIdx.x;
    int x = bid & 7, g = bid >> 3;
    int pss, nb, F, logF;
    if constexpr (FACT == 64) {
        pss = x >> 2; nb = g * 4 + (x & 3); F = 32; logF = 5;
        if (nb >= NN / 8) return;
    } else {
        if (x < 5) { pss = 0; nb = g * 5 + x;       F = 32; logF = 5; if (nb >= NN / 8)  return; }
        else       { pss = 1; nb = g * 3 + (x - 5); F = 16; logF = 4; if (nb >= NN / 16) return; }
    }
    int t = threadIdx.x;
    int f = t & (F - 1);
    int node = nb * (256 >> logF) + (t >> logF);
    const unsigned short* ah = a + (size_t)pss * HALFE;

    float acc = diag[node] * bf2f(ah[(size_t)node * 32 + f]);
    int j = rs[node], j1 = rs[node + 1];
    for (; j + 8 <= j1; j += 8) {
        unsigned cw[8];
        #pragma unroll
        for (int u = 0; u < 8; ++u) cw[u] = csr[j + u];
        float v[8];
        #pragma unroll
        for (int u = 0; u < 8; ++u)
            v[u] = bf2f(ah[(size_t)(cw[u] & 0xFFFFu) * 32 + f]);
        #pragma unroll
        for (int u = 0; u < 8; ++u)
            acc = fmaf(bf2f((unsigned short)(cw[u] >> 16)), v[u], acc);
    }
    for (; j < j1; ++j) {
        unsigned cw = csr[j];
        acc = fmaf(bf2f((unsigned short)(cw >> 16)),
                   bf2f(ah[(size_t)(cw & 0xFFFFu) * 32 + f]), acc);
    }
    int fg = pss * 32 + f;
    float r = alphaL * acc + beta1 * bf2f(p1[(size_t)pss * HALFE + (size_t)node * 32 + f]);
    if (beta2 != 0.f) r = fmaf(beta2, bf2f(p2[(size_t)pss * HALFE + (size_t)node * 32 + f]), r);
    if (bias) r += bias[fg];
    if (doRelu) r = fmaxf(r, 0.f);
    if constexpr (FINAL) {
        if (fg < CC) ((float*)out)[(size_t)node * CC + fg] = r;
    } else {
        OUT_T o;
        if constexpr (sizeof(OUT_T) == 2) o = f2bf(r); else o = r;
        out[(size_t)pss * HALFE + (size_t)node * 32 + f] = o;
    }
}

// ---------- weight prep: transposed bf16 hi/lo tables, K-contiguous ----------
__global__ __launch_bounds__(256) void convw_kernel(
    const float* __restrict__ W1, const float* __restrict__ W2,
    unsigned short* __restrict__ W1t_hi, unsigned short* __restrict__ W1t_lo,
    unsigned short* __restrict__ W2t_hi, unsigned short* __restrict__ W2t_lo) {
    int tid = blockIdx.x * 256 + threadIdx.x;
    if (tid < 512 * 64) {
        int row = tid >> 7, kk = tid & 127;      // row = ct*64 + j
        int ct = row >> 6, j = row & 63;
        float v = W1[((size_t)(ct * 128 + kk)) * 64 + j];
        unsigned short h = f2bf(v);
        W1t_hi[tid] = h;
        W1t_lo[tid] = f2bf(v - bf2f(h));
    } else {
        int t2 = tid - 512 * 64;
        if (t2 >= 4 * 64 * 64) return;
        int row = t2 >> 6, kk = t2 & 63;         // row = kt*64 + j
        int kt = row >> 6, j = row & 63;
        float v = (j < CC) ? W2[((size_t)(kt * 64 + kk)) * CC + j] : 0.f;
        unsigned short h = f2bf(v);
        W2t_hi[t2] = h;
        W2t_lo[t2] = f2bf(v - bf2f(h));
    }
}

// ---------- MFMA GEMM -> bf16 half-slabs ----------
// A: fp32; AHALF=0: row-major [N][KF*32]; AHALF=1: half-slab [2][N][32].
// Split-precision: A*B ~= Ah*Bh + Ah*Bl + Al*Bh  (fp32-equivalent accuracy).
template <int KF, int AHALF>
__global__ __launch_bounds__(256) void gemm_mfma_kernel(
    const float* __restrict__ A, const unsigned short* __restrict__ Wt_hi,
    const unsigned short* __restrict__ Wt_lo, unsigned short* __restrict__ Yb) {
    constexpr int KK = KF * 32;
    int lane = threadIdx.x & 63;
    int ct   = threadIdx.x >> 6;                // wave = output slab
    int l15  = lane & 15;
    int lg   = lane >> 4;
    int m0   = blockIdx.x * 32;

    f32x4 acc[2][4];
    #pragma unroll
    for (int i = 0; i < 2; ++i)
        #pragma unroll
        for (int j = 0; j < 4; ++j)
            acc[i][j] = (f32x4){0.f, 0.f, 0.f, 0.f};

    #pragma unroll
    for (int kf = 0; kf < KF; ++kf) {
        int k0 = kf * 32 + lg * 8;
        BF8 bh[4], bl[4];
        #pragma unroll
        for (int nf = 0; nf < 4; ++nf) {
            size_t addr = (size_t)(ct * 64 + nf * 16 + l15) * KK + k0;
            bh[nf].v = *reinterpret_cast<const bf16x8*>(Wt_hi + addr);
            bl[nf].v = *reinterpret_cast<const bf16x8*>(Wt_lo + addr);
        }
        BF8 ah[2], al[2];
        #pragma unroll
        for (int ms = 0; ms < 2; ++ms) {
            int n = m0 + ms * 16 + l15;
            if (n >= NN) n = NN - 1;             // clamp (stores are guarded)
            const float* ap;
            if constexpr (AHALF)
                ap = A + (size_t)kf * HALFE + (size_t)n * 32 + lg * 8;
            else
                ap = A + (size_t)n * KK + k0;
            float4 f0 = *(const float4*)(ap);
            float4 f1 = *(const float4*)(ap + 4);
            float fv[8] = {f0.x, f0.y, f0.z, f0.w, f1.x, f1.y, f1.z, f1.w};
            #pragma unroll
            for (int u = 0; u < 8; ++u) {
                unsigned short h = f2bf(fv[u]);
                ah[ms].u[u] = h;
                al[ms].u[u] = f2bf(fv[u] - bf2f(h));
            }
        }
        #pragma unroll
        for (int ms = 0; ms < 2; ++ms)
            #pragma unroll
            for (int nf = 0; nf < 4; ++nf) {
                acc[ms][nf] = __builtin_amdgcn_mfma_f32_16x16x32_bf16(
                    ah[ms].v, bh[nf].v, acc[ms][nf], 0, 0, 0);
                acc[ms][nf] = __builtin_amdgcn_mfma_f32_16x16x32_bf16(
                    ah[ms].v, bl[nf].v, acc[ms][nf], 0, 0, 0);
                acc[ms][nf] = __builtin_amdgcn_mfma_f32_16x16x32_bf16(
                    al[ms].v, bh[nf].v, acc[ms][nf], 0, 0, 0);
            }
    }

    // store to half-slab: global col = nf*16+l15 -> half nf>>1, offset (nf&1)*16+l15
    unsigned short* slab = Yb + (size_t)ct * NN * 64;
    #pragma unroll
    for (int ms = 0; ms < 2; ++ms)
        #pragma unroll
        for (int r = 0; r < 4; ++r) {
            int n = m0 + ms * 16 + lg * 4 + r;
            if (n < NN) {
                #pragma unroll
                for (int nf = 0; nf < 4; ++nf)
                    slab[(size_t)(nf >> 1) * HALFE + (size_t)n * 32 + (nf & 1) * 16 + l15]
                        = f2bf(acc[ms][nf][r]);
            }
        }
}

// ---------- launcher ----------
extern "C" void kernel_launch(void* const* d_in, const int* in_sizes, int n_in,
                              void* d_out, int out_size, void* d_ws, size_t ws_size,
                              hipStream_t stream) {
    const float* x    = (const float*)d_in[0];
    const int*   eidx = (const int*)d_in[1];
    const float* ew   = (const float*)d_in[2];
    const float* W1   = (const float*)d_in[3];
    const float* b1   = (const float*)d_in[4];
    const float* W2   = (const float*)d_in[5];
    const float* b2   = (const float*)d_in[6];
    float* out = (float*)d_out;

    const int* src = eidx;
    const int* dst = eidx + EE;

    // workspace carve-up  (total ~91 MB)
    float* p = (float*)d_ws;
    unsigned int* csr = (unsigned int*)p;  p += (size_t)EE;           // 6.4 MB
    float* dis  = p;                  p += ((NN + 63) / 64) * 64;
    float* diag = p;                  p += ((NN + 63) / 64) * 64;
    unsigned short* Yb = (unsigned short*)p;  p += (size_t)NN * 128;  // 4 bf16 slabs, 25.6 MB
    unsigned short* u  = (unsigned short*)p;  p += (size_t)NN * 32;   // bf16 [2][N][32], 6.4 MB
    unsigned short* v  = (unsigned short*)p;  p += (size_t)NN * 32;   // 6.4 MB
    float* h    = p;                  p += (size_t)NN * 64;           // fp32 [2][N][32], 12.8 MB
    float* scratch = p;               p += (size_t)PA * SB * BCAP * 2; // 32 MB (buckets)
    int* row_start = (int*)p;             // NN+1
    int* counts    = row_start + NN + 1;  // PA*SB
    int* sbase     = counts + PA * SB;    // SB+1

    // setup scratch: pdeg (12.8 MB) and buckets (32 MB) SHARE the 32 MB region.
    float* pdeg    = scratch;             // 64*NN floats = 12.8 MB
    uint2* buckets = (uint2*)scratch;     // PA*SB*BCAP*8 B = 32 MB
    unsigned short* W1t_hi = (unsigned short*)scratch;   // 32768 bf16
    unsigned short* W1t_lo = W1t_hi + 512 * 64;
    unsigned short* W2t_hi = W1t_lo + 512 * 64;          // 16384 bf16
    unsigned short* W2t_lo = W2t_hi + 4 * 64 * 64;
    // layer-1 slab views (each [2][N][32])
    unsigned short* y0b = Yb;
    unsigned short* y1b = Yb + (size_t)1 * NN * 64;
    unsigned short* y2b = Yb + (size_t)2 * NN * 64;
    unsigned short* y3b = Yb + (size_t)3 * NN * 64;
    // layer-2 slabs alias Yb (y-slabs dead after h)
    unsigned short* Zb = Yb;
    unsigned short* z0 = Zb;
    unsigned short* z1 = Zb + (size_t)1 * NN * 64;
    unsigned short* z2 = Zb + (size_t)2 * NN * 64;
    unsigned short* z3 = Zb + (size_t)3 * NN * 64;
    unsigned short* u2 = u;
    unsigned short* v2 = v;

    const int B = 256;
    deg_hist_kernel<<<NCH * NSL, 1024, 0, stream>>>(src, ew, pdeg);
    reduce_kernel<<<(NN + B - 1) / B, B, 0, stream>>>(pdeg, dis, diag);
    bucketA_kernel<<<PA, 256, 0, stream>>>(src, dst, ew, dis, buckets, counts);
    scanS_kernel<<<1, 256, 0, stream>>>(counts, sbase);
    bucketB_kernel<<<SB, 256, 0, stream>>>(buckets, counts, sbase, row_start, csr);
    convw_kernel<<<192, 256, 0, stream>>>(W1, W2, W1t_hi, W1t_lo, W2t_hi, W2t_lo);

    int ggrid = (NN + 31) / 32;
    const int PG64 = 1563 * 8;   // FACT=64: 2 passes x 6250 node-blocks, XCD split 4/4
    const int PG48 = 1250 * 8;   // FACT=48: pass0 6250 blocks on 5 XCDs, pass1 3125 on 3

    // ---- layer 1: MFMA-project to bf16 half-slabs, then 3 full-width props ----
    gemm_mfma_kernel<4, 0><<<ggrid, 256, 0, stream>>>(x, W1t_hi, W1t_lo, Yb);
    prop3_kernel<64, unsigned short, 0><<<PG64, 256, 0, stream>>>(
        y3b, 4.f, y2b, 2.f, nullptr, 0.f,
        nullptr, 0, diag, row_start, csr, u);                  // u = 4*L(y3) + 2*y2
    prop3_kernel<64, unsigned short, 0><<<PG64, 256, 0, stream>>>(
        u, 1.f, y1b, 1.f, y3b, -3.f,
        nullptr, 0, diag, row_start, csr, v);                  // v = L(u) + y1 - 3*y3
    prop3_kernel<64, float, 0><<<PG64, 256, 0, stream>>>(
        v, 1.f, y0b, 1.f, y2b, -1.f,
        b1, 1, diag, row_start, csr, h);                       // h = relu(L(v)+y0-y2+b1)

    // ---- layer 2: MFMA-project (cols 40..63 auto-zero via padded Wt), 3 props ----
    gemm_mfma_kernel<2, 1><<<ggrid, 256, 0, stream>>>(h, W2t_hi, W2t_lo, Zb);
    prop3_kernel<48, unsigned short, 0><<<PG48, 256, 0, stream>>>(
        z3, 4.f, z2, 2.f, nullptr, 0.f,
        nullptr, 0, diag, row_start, csr, u2);                 // u2 = 4*L(z3) + 2*z2
    prop3_kernel<48, unsigned short, 0><<<PG48, 256, 0, stream>>>(
        u2, 1.f, z1, 1.f, z3, -3.f,
        nullptr, 0, diag, row_start, csr, v2);                 // v2 = L(u2) + z1 - 3*z3
    prop3_kernel<48, float, 1><<<PG48, 256, 0, stream>>>(
        v2, 1.f, z0, 1.f, z2, -1.f,
        b2, 0, diag, row_start, csr, (float*)out);             // out = L(v2)+z0-z2+b2
}

// Round 3
// 466.010 us; speedup vs baseline: 1.1464x; 1.1015x over previous
//
#include <hip/hip_runtime.h>

// Problem constants
#define NN 50000
#define EE 1600000
#define FF 128
#define HH 64
#define CC 40

// deg hist: 64 edge-chunks x 4 node-slices = 256 blocks
#define NCH 64
#define CHE (EE / NCH)         // 25000
#define NSL 4
#define SLN (NN / NSL)         // 12500

// bucket sort: 250 producers x 250 dst-slices (200 nodes each), capacity 64
#define PA 250
#define EPP (EE / PA)          // 6400
#define SB 250
#define SLNB 200               // NN / SB
#define BCAP 64

// half-slab: every feature slab is [2][NN][32] (3.2 MB halves -> per-XCD L2 resident)
#define HALFE ((size_t)NN * 32)

// ---------- bf16 helpers (storage-only; math in fp32) ----------
static __device__ __forceinline__ float bf2f(unsigned short u) {
    union { unsigned int i; float f; } c; c.i = ((unsigned int)u) << 16; return c.f;
}
static __device__ __forceinline__ unsigned short f2bf(float x) {  // RNE
    union { float f; unsigned int i; } c; c.f = x;
    unsigned int r = c.i + 0x7FFFu + ((c.i >> 16) & 1u);
    return (unsigned short)(r >> 16);
}
// unpack 2 bf16 packed in a u32: lo = feature i, hi = feature i+1
static __device__ __forceinline__ void up2(unsigned w, float& lo, float& hi) {
    union { unsigned u; float f; } a, b;
    a.u = w << 16; b.u = w & 0xFFFF0000u;
    lo = a.f; hi = b.f;
}

// MFMA fragment types
typedef __attribute__((ext_vector_type(8))) short bf16x8;
typedef __attribute__((ext_vector_type(4))) float f32x4;
union BF8 { bf16x8 v; unsigned short u[8]; };

// ---------- deg histogram ----------
__global__ __launch_bounds__(1024) void deg_hist_kernel(
    const int* __restrict__ src, const float* __restrict__ w,
    float* __restrict__ pdeg) {
    __shared__ float ldeg[SLN];
    int s = blockIdx.x % NSL;
    int c = blockIdx.x / NSL;
    int base = s * SLN;
    for (int i = threadIdx.x; i < SLN; i += 1024) ldeg[i] = 0.f;
    __syncthreads();
    int e0 = c * CHE;
    for (int e = e0 + threadIdx.x; e < e0 + CHE; e += 1024) {
        int se = src[e];
        unsigned us = (unsigned)(se - base);
        if (us < SLN) atomicAdd(&ldeg[us], w[e]);
    }
    __syncthreads();
    for (int i = threadIdx.x; i < SLN; i += 1024)
        pdeg[(size_t)c * NN + base + i] = ldeg[i];
}

__global__ void reduce_kernel(const float* __restrict__ pdeg,
                              float* __restrict__ dis, float* __restrict__ diag) {
    int n = blockIdx.x * blockDim.x + threadIdx.x;
    if (n >= NN) return;
    float dsum = 0.f;
    for (int c = 0; c < NCH; ++c) dsum += pdeg[(size_t)c * NN + n];
    dis[n]  = (dsum > 0.f) ? rsqrtf(fmaxf(dsum, 1e-12f)) : 0.f;
    diag[n] = (dsum > 0.f) ? 0.f : -1.f;
}

// ---------- phase A: bin edges by dst-slice ----------
__global__ __launch_bounds__(256) void bucketA_kernel(
    const int* __restrict__ src, const int* __restrict__ dst,
    const float* __restrict__ w, const float* __restrict__ dis,
    uint2* __restrict__ buckets, int* __restrict__ counts) {
    __shared__ int lcnt[SB];
    int p = blockIdx.x;
    for (int i = threadIdx.x; i < SB; i += 256) lcnt[i] = 0;
    __syncthreads();
    int e0 = p * EPP;
    for (int e = e0 + threadIdx.x; e < e0 + EPP; e += 256) {
        int de = dst[e], se = src[e];
        int sl = de / SLNB;
        int dl = de - sl * SLNB;
        float wn = -dis[se] * w[e] * dis[de];
        unsigned lo = (unsigned)se | ((unsigned)f2bf(wn) << 16);
        int idx = atomicAdd(&lcnt[sl], 1);
        buckets[((size_t)p * SB + sl) * BCAP + idx] = make_uint2(lo, (unsigned)dl);
    }
    __syncthreads();
    for (int i = threadIdx.x; i < SB; i += 256) counts[p * SB + i] = lcnt[i];
}

// ---------- exclusive scan of per-slice totals ----------
__global__ void scanS_kernel(const int* __restrict__ counts, int* __restrict__ sbase) {
    __shared__ int sh[256];
    int t = threadIdx.x;
    int total = 0;
    if (t < SB)
        for (int p = 0; p < PA; ++p) total += counts[p * SB + t];
    sh[t] = total;
    __syncthreads();
    for (int off = 1; off < 256; off <<= 1) {
        int x = (t >= off) ? sh[t - off] : 0;
        __syncthreads();
        sh[t] += x;
        __syncthreads();
    }
    if (t < SB) sbase[t] = sh[t] - total;
    if (t == SB - 1) sbase[SB] = sh[t];
}

// ---------- phase B v2: counts in LDS + 16-lane bucket subgroups ----------
__global__ __launch_bounds__(256) void bucketB_kernel(
    const uint2* __restrict__ buckets, const int* __restrict__ counts,
    const int* __restrict__ sbase,
    int* __restrict__ row_start, unsigned int* __restrict__ csr) {
    __shared__ int lcounts[PA];
    __shared__ int lhist[SLNB];
    __shared__ int sh[256];
    int s = blockIdx.x;
    int t = threadIdx.x;
    if (t < PA) lcounts[t] = counts[t * SB + s];
    for (int i = t; i < SLNB; i += 256) lhist[i] = 0;
    __syncthreads();
    int g = t >> 4, l16 = t & 15;   // 16 subgroups x 16 lanes
    for (int p = g; p < PA; p += 16) {
        int c = lcounts[p];
        const uint2* b = buckets + ((size_t)p * SB + s) * BCAP;
        for (int i = l16; i < c; i += 16)
            atomicAdd(&lhist[b[i].y], 1);
    }
    __syncthreads();
    int v = (t < SLNB) ? lhist[t] : 0;
    sh[t] = v;
    __syncthreads();
    for (int off = 1; off < 256; off <<= 1) {
        int x = (t >= off) ? sh[t - off] : 0;
        __syncthreads();
        sh[t] += x;
        __syncthreads();
    }
    int base = sbase[s];
    if (t < SLNB) {
        int excl = sh[t] - v;
        row_start[s * SLNB + t] = base + excl;
        lhist[t] = base + excl;          // absolute cursor
    }
    if (s == SB - 1 && t == 0) row_start[NN] = sbase[SB];
    __syncthreads();
    for (int p = g; p < PA; p += 16) {
        int c = lcounts[p];
        const uint2* b = buckets + ((size_t)p * SB + s) * BCAP;
        for (int i = l16; i < c; i += 16) {
            uint2 en = b[i];
            int pos = atomicAdd(&lhist[en.y], 1);
            csr[pos] = en.x;
        }
    }
}

// ---------- propagation v4: 4 features/lane (uint2 gathers), group-of-GL lanes ----------
// Pass chosen by blockIdx%8 for XCD L2 affinity (halves are 3.2 MB, L2-resident).
// FACT=64: GL=8, passes on XCD split 4/4.
// FACT=48 mid:  pass0 F=32 GL=8 on 5 XCDs, pass1 F=16 GL=4 on 3 XCDs.
// FACT=48 FINAL: pass1 only needs output features 32..39 -> GL=2, split 6/2.
template <int FACT, typename OUT_T, int FINAL>
__global__ __launch_bounds__(256) void prop4_kernel(
    const unsigned short* __restrict__ a, float alphaL,
    const unsigned short* __restrict__ p1, float beta1,
    const unsigned short* __restrict__ p2, float beta2,
    const float* __restrict__ bias, int doRelu,
    const float* __restrict__ diag, const int* __restrict__ rs,
    const unsigned int* __restrict__ csr, OUT_T* __restrict__ out) {

    int bid = blockIdx.x;
    int xc = bid & 7, g = bid >> 3;
    int pss, nb, logGL;
    if constexpr (FACT == 64) {
        pss = xc >> 2; nb = g * 4 + (xc & 3); logGL = 3;
        if (nb >= (NN + 31) / 32) return;
    } else if constexpr (!FINAL) {
        if (xc < 5) { pss = 0; nb = g * 5 + xc;       logGL = 3; if (nb >= (NN + 31) / 32)  return; }
        else        { pss = 1; nb = g * 3 + (xc - 5); logGL = 2; if (nb >= (NN + 63) / 64)  return; }
    } else {
        if (xc < 6) { pss = 0; nb = g * 6 + xc;       logGL = 3; if (nb >= (NN + 31) / 32)  return; }
        else        { pss = 1; nb = g * 2 + (xc - 6); logGL = 1; if (nb >= (NN + 127) / 128) return; }
    }
    int t = threadIdx.x;
    int gl = t & ((1 << logGL) - 1);
    int node = nb * (256 >> logGL) + (t >> logGL);
    if (node >= NN) return;
    int f4 = gl << 2;                         // feature offset within the 32-wide half
    const unsigned short* ah = a + (size_t)pss * HALFE;

    uint2 av = *(const uint2*)(ah + (size_t)node * 32 + f4);
    float d = diag[node];
    float a0, a1, a2, a3; up2(av.x, a0, a1); up2(av.y, a2, a3);
    float acc0 = d * a0, acc1 = d * a1, acc2 = d * a2, acc3 = d * a3;

    int j = rs[node], j1 = rs[node + 1];
    for (; j + 4 <= j1; j += 4) {
        unsigned cw0 = csr[j], cw1 = csr[j + 1], cw2 = csr[j + 2], cw3 = csr[j + 3];
        uint2 g0 = *(const uint2*)(ah + (size_t)(cw0 & 0xFFFFu) * 32 + f4);
        uint2 g1 = *(const uint2*)(ah + (size_t)(cw1 & 0xFFFFu) * 32 + f4);
        uint2 g2 = *(const uint2*)(ah + (size_t)(cw2 & 0xFFFFu) * 32 + f4);
        uint2 g3 = *(const uint2*)(ah + (size_t)(cw3 & 0xFFFFu) * 32 + f4);
        float w0 = bf2f((unsigned short)(cw0 >> 16));
        float w1 = bf2f((unsigned short)(cw1 >> 16));
        float w2 = bf2f((unsigned short)(cw2 >> 16));
        float w3 = bf2f((unsigned short)(cw3 >> 16));
        float l0, h0, l1, h1;
        up2(g0.x, l0, h0); up2(g0.y, l1, h1);
        acc0 = fmaf(w0, l0, acc0); acc1 = fmaf(w0, h0, acc1);
        acc2 = fmaf(w0, l1, acc2); acc3 = fmaf(w0, h1, acc3);
        up2(g1.x, l0, h0); up2(g1.y, l1, h1);
        acc0 = fmaf(w1, l0, acc0); acc1 = fmaf(w1, h0, acc1);
        acc2 = fmaf(w1, l1, acc2); acc3 = fmaf(w1, h1, acc3);
        up2(g2.x, l0, h0); up2(g2.y, l1, h1);
        acc0 = fmaf(w2, l0, acc0); acc1 = fmaf(w2, h0, acc1);
        acc2 = fmaf(w2, l1, acc2); acc3 = fmaf(w2, h1, acc3);
        up2(g3.x, l0, h0); up2(g3.y, l1, h1);
        acc0 = fmaf(w3, l0, acc0); acc1 = fmaf(w3, h0, acc1);
        acc2 = fmaf(w3, l1, acc2); acc3 = fmaf(w3, h1, acc3);
    }
    for (; j < j1; ++j) {
        unsigned cw = csr[j];
        uint2 gv = *(const uint2*)(ah + (size_t)(cw & 0xFFFFu) * 32 + f4);
        float w = bf2f((unsigned short)(cw >> 16));
        float l0, h0, l1, h1; up2(gv.x, l0, h0); up2(gv.y, l1, h1);
        acc0 = fmaf(w, l0, acc0); acc1 = fmaf(w, h0, acc1);
        acc2 = fmaf(w, l1, acc2); acc3 = fmaf(w, h1, acc3);
    }

    int fg = pss * 32 + f4;
    size_t off = (size_t)pss * HALFE + (size_t)node * 32 + f4;
    uint2 q1 = *(const uint2*)(p1 + off);
    float s0, s1, s2, s3; up2(q1.x, s0, s1); up2(q1.y, s2, s3);
    float r0 = alphaL * acc0 + beta1 * s0;
    float r1 = alphaL * acc1 + beta1 * s1;
    float r2 = alphaL * acc2 + beta1 * s2;
    float r3 = alphaL * acc3 + beta1 * s3;
    if (beta2 != 0.f) {
        uint2 q2 = *(const uint2*)(p2 + off);
        up2(q2.x, s0, s1); up2(q2.y, s2, s3);
        r0 = fmaf(beta2, s0, r0); r1 = fmaf(beta2, s1, r1);
        r2 = fmaf(beta2, s2, r2); r3 = fmaf(beta2, s3, r3);
    }
    if constexpr (FINAL) {
        if (fg < CC) {   // fg multiple of 4 => fg+3 < CC too
            r0 += bias[fg]; r1 += bias[fg + 1]; r2 += bias[fg + 2]; r3 += bias[fg + 3];
            float4 st = make_float4(r0, r1, r2, r3);
            *(float4*)((float*)out + (size_t)node * CC + fg) = st;
        }
    } else {
        if (bias) { r0 += bias[fg]; r1 += bias[fg + 1]; r2 += bias[fg + 2]; r3 += bias[fg + 3]; }
        if (doRelu) {
            r0 = fmaxf(r0, 0.f); r1 = fmaxf(r1, 0.f);
            r2 = fmaxf(r2, 0.f); r3 = fmaxf(r3, 0.f);
        }
        if constexpr (sizeof(OUT_T) == 2) {
            ushort4 st; st.x = f2bf(r0); st.y = f2bf(r1); st.z = f2bf(r2); st.w = f2bf(r3);
            *(ushort4*)(out + off) = st;
        } else {
            float4 st = make_float4(r0, r1, r2, r3);
            *(float4*)((float*)out + off) = st;
        }
    }
}

// ---------- weight prep: transposed bf16 hi/lo tables, K-contiguous ----------
__global__ __launch_bounds__(256) void convw_kernel(
    const float* __restrict__ W1, const float* __restrict__ W2,
    unsigned short* __restrict__ W1t_hi, unsigned short* __restrict__ W1t_lo,
    unsigned short* __restrict__ W2t_hi, unsigned short* __restrict__ W2t_lo) {
    int tid = blockIdx.x * 256 + threadIdx.x;
    if (tid < 512 * 64) {
        int row = tid >> 7, kk = tid & 127;      // row = ct*64 + j
        int ct = row >> 6, j = row & 63;
        float v = W1[((size_t)(ct * 128 + kk)) * 64 + j];
        unsigned short h = f2bf(v);
        W1t_hi[tid] = h;
        W1t_lo[tid] = f2bf(v - bf2f(h));
    } else {
        int t2 = tid - 512 * 64;
        if (t2 >= 4 * 64 * 64) return;
        int row = t2 >> 6, kk = t2 & 63;         // row = kt*64 + j
        int kt = row >> 6, j = row & 63;
        float v = (j < CC) ? W2[((size_t)(kt * 64 + kk)) * CC + j] : 0.f;
        unsigned short h = f2bf(v);
        W2t_hi[t2] = h;
        W2t_lo[t2] = f2bf(v - bf2f(h));
    }
}

// ---------- MFMA GEMM -> bf16 half-slabs ----------
// A: fp32; AHALF=0: row-major [N][KF*32]; AHALF=1: half-slab [2][N][32].
// Split-precision: A*B ~= Ah*Bh + Ah*Bl + Al*Bh  (fp32-equivalent accuracy).
template <int KF, int AHALF>
__global__ __launch_bounds__(256) void gemm_mfma_kernel(
    const float* __restrict__ A, const unsigned short* __restrict__ Wt_hi,
    const unsigned short* __restrict__ Wt_lo, unsigned short* __restrict__ Yb) {
    constexpr int KK = KF * 32;
    int lane = threadIdx.x & 63;
    int ct   = threadIdx.x >> 6;                // wave = output slab
    int l15  = lane & 15;
    int lg   = lane >> 4;
    int m0   = blockIdx.x * 32;

    f32x4 acc[2][4];
    #pragma unroll
    for (int i = 0; i < 2; ++i)
        #pragma unroll
        for (int j = 0; j < 4; ++j)
            acc[i][j] = (f32x4){0.f, 0.f, 0.f, 0.f};

    #pragma unroll
    for (int kf = 0; kf < KF; ++kf) {
        int k0 = kf * 32 + lg * 8;
        BF8 bh[4], bl[4];
        #pragma unroll
        for (int nf = 0; nf < 4; ++nf) {
            size_t addr = (size_t)(ct * 64 + nf * 16 + l15) * KK + k0;
            bh[nf].v = *reinterpret_cast<const bf16x8*>(Wt_hi + addr);
            bl[nf].v = *reinterpret_cast<const bf16x8*>(Wt_lo + addr);
        }
        BF8 ah[2], al[2];
        #pragma unroll
        for (int ms = 0; ms < 2; ++ms) {
            int n = m0 + ms * 16 + l15;
            if (n >= NN) n = NN - 1;             // clamp (stores are guarded)
            const float* ap;
            if constexpr (AHALF)
                ap = A + (size_t)kf * HALFE + (size_t)n * 32 + lg * 8;
            else
                ap = A + (size_t)n * KK + k0;
            float4 f0 = *(const float4*)(ap);
            float4 f1 = *(const float4*)(ap + 4);
            float fv[8] = {f0.x, f0.y, f0.z, f0.w, f1.x, f1.y, f1.z, f1.w};
            #pragma unroll
            for (int u = 0; u < 8; ++u) {
                unsigned short h = f2bf(fv[u]);
                ah[ms].u[u] = h;
                al[ms].u[u] = f2bf(fv[u] - bf2f(h));
            }
        }
        #pragma unroll
        for (int ms = 0; ms < 2; ++ms)
            #pragma unroll
            for (int nf = 0; nf < 4; ++nf) {
                acc[ms][nf] = __builtin_amdgcn_mfma_f32_16x16x32_bf16(
                    ah[ms].v, bh[nf].v, acc[ms][nf], 0, 0, 0);
                acc[ms][nf] = __builtin_amdgcn_mfma_f32_16x16x32_bf16(
                    ah[ms].v, bl[nf].v, acc[ms][nf], 0, 0, 0);
                acc[ms][nf] = __builtin_amdgcn_mfma_f32_16x16x32_bf16(
                    al[ms].v, bh[nf].v, acc[ms][nf], 0, 0, 0);
            }
    }

    // store to half-slab: global col = nf*16+l15 -> half nf>>1, offset (nf&1)*16+l15
    unsigned short* slab = Yb + (size_t)ct * NN * 64;
    #pragma unroll
    for (int ms = 0; ms < 2; ++ms)
        #pragma unroll
        for (int r = 0; r < 4; ++r) {
            int n = m0 + ms * 16 + lg * 4 + r;
            if (n < NN) {
                #pragma unroll
                for (int nf = 0; nf < 4; ++nf)
                    slab[(size_t)(nf >> 1) * HALFE + (size_t)n * 32 + (nf & 1) * 16 + l15]
                        = f2bf(acc[ms][nf][r]);
            }
        }
}

// ---------- launcher ----------
extern "C" void kernel_launch(void* const* d_in, const int* in_sizes, int n_in,
                              void* d_out, int out_size, void* d_ws, size_t ws_size,
                              hipStream_t stream) {
    const float* x    = (const float*)d_in[0];
    const int*   eidx = (const int*)d_in[1];
    const float* ew   = (const float*)d_in[2];
    const float* W1   = (const float*)d_in[3];
    const float* b1   = (const float*)d_in[4];
    const float* W2   = (const float*)d_in[5];
    const float* b2   = (const float*)d_in[6];
    float* out = (float*)d_out;

    const int* src = eidx;
    const int* dst = eidx + EE;

    // workspace carve-up  (total ~91 MB)
    float* p = (float*)d_ws;
    unsigned int* csr = (unsigned int*)p;  p += (size_t)EE;           // 6.4 MB
    float* dis  = p;                  p += ((NN + 63) / 64) * 64;
    float* diag = p;                  p += ((NN + 63) / 64) * 64;
    unsigned short* Yb = (unsigned short*)p;  p += (size_t)NN * 128;  // 4 bf16 slabs, 25.6 MB
    unsigned short* u  = (unsigned short*)p;  p += (size_t)NN * 32;   // bf16 [2][N][32], 6.4 MB
    unsigned short* v  = (unsigned short*)p;  p += (size_t)NN * 32;   // 6.4 MB
    float* h    = p;                  p += (size_t)NN * 64;           // fp32 [2][N][32], 12.8 MB
    float* scratch = p;               p += (size_t)PA * SB * BCAP * 2; // 32 MB (buckets)
    int* row_start = (int*)p;             // NN+1
    int* counts    = row_start + NN + 1;  // PA*SB
    int* sbase     = counts + PA * SB;    // SB+1

    // setup scratch: pdeg (12.8 MB) and buckets (32 MB) SHARE the 32 MB region.
    float* pdeg    = scratch;             // 64*NN floats = 12.8 MB
    uint2* buckets = (uint2*)scratch;     // PA*SB*BCAP*8 B = 32 MB
    unsigned short* W1t_hi = (unsigned short*)scratch;   // 32768 bf16
    unsigned short* W1t_lo = W1t_hi + 512 * 64;
    unsigned short* W2t_hi = W1t_lo + 512 * 64;          // 16384 bf16
    unsigned short* W2t_lo = W2t_hi + 4 * 64 * 64;
    // layer-1 slab views (each [2][N][32])
    unsigned short* y0b = Yb;
    unsigned short* y1b = Yb + (size_t)1 * NN * 64;
    unsigned short* y2b = Yb + (size_t)2 * NN * 64;
    unsigned short* y3b = Yb + (size_t)3 * NN * 64;
    // layer-2 slabs alias Yb (y-slabs dead after h)
    unsigned short* Zb = Yb;
    unsigned short* z0 = Zb;
    unsigned short* z1 = Zb + (size_t)1 * NN * 64;
    unsigned short* z2 = Zb + (size_t)2 * NN * 64;
    unsigned short* z3 = Zb + (size_t)3 * NN * 64;
    unsigned short* u2 = u;
    unsigned short* v2 = v;

    const int B = 256;
    deg_hist_kernel<<<NCH * NSL, 1024, 0, stream>>>(src, ew, pdeg);
    reduce_kernel<<<(NN + B - 1) / B, B, 0, stream>>>(pdeg, dis, diag);
    bucketA_kernel<<<PA, 256, 0, stream>>>(src, dst, ew, dis, buckets, counts);
    scanS_kernel<<<1, 256, 0, stream>>>(counts, sbase);
    bucketB_kernel<<<SB, 256, 0, stream>>>(buckets, counts, sbase, row_start, csr);
    convw_kernel<<<192, 256, 0, stream>>>(W1, W2, W1t_hi, W1t_lo, W2t_hi, W2t_lo);

    int ggrid = (NN + 31) / 32;
    const int NB32 = (NN + 31) / 32;     // 1563
    const int PG64  = ((NB32 + 3) / 4) * 8;  // 391*8 = 3128
    const int PG48  = ((NB32 + 4) / 5) * 8;  // 313*8 = 2504
    const int PG48F = ((NB32 + 5) / 6) * 8;  // 261*8 = 2088

    // ---- layer 1: MFMA-project to bf16 half-slabs, then 3 full-width props ----
    gemm_mfma_kernel<4, 0><<<ggrid, 256, 0, stream>>>(x, W1t_hi, W1t_lo, Yb);
    prop4_kernel<64, unsigned short, 0><<<PG64, 256, 0, stream>>>(
        y3b, 4.f, y2b, 2.f, nullptr, 0.f,
        nullptr, 0, diag, row_start, csr, u);                  // u = 4*L(y3) + 2*y2
    prop4_kernel<64, unsigned short, 0><<<PG64, 256, 0, stream>>>(
        u, 1.f, y1b, 1.f, y3b, -3.f,
        nullptr, 0, diag, row_start, csr, v);                  // v = L(u) + y1 - 3*y3
    prop4_kernel<64, float, 0><<<PG64, 256, 0, stream>>>(
        v, 1.f, y0b, 1.f, y2b, -1.f,
        b1, 1, diag, row_start, csr, h);                       // h = relu(L(v)+y0-y2+b1)

    // ---- layer 2: MFMA-project (cols 40..63 auto-zero via padded Wt), 3 props ----
    gemm_mfma_kernel<2, 1><<<ggrid, 256, 0, stream>>>(h, W2t_hi, W2t_lo, Zb);
    prop4_kernel<48, unsigned short, 0><<<PG48, 256, 0, stream>>>(
        z3, 4.f, z2, 2.f, nullptr, 0.f,
        nullptr, 0, diag, row_start, csr, u2);                 // u2 = 4*L(z3) + 2*z2
    prop4_kernel<48, unsigned short, 0><<<PG48, 256, 0, stream>>>(
        u2, 1.f, z1, 1.f, z3, -3.f,
        nullptr, 0, diag, row_start, csr, v2);                 // v2 = L(u2) + z1 - 3*z3
    prop4_kernel<48, float, 1><<<PG48F, 256, 0, stream>>>(
        v2, 1.f, z0, 1.f, z2, -1.f,
        b2, 0, diag, row_start, csr, (float*)out);             // out = L(v2)+z0-z2+b2
}